// Round 1
// baseline (562.994 us; speedup 1.0000x reference)
//
#include <hip/hip_runtime.h>
#include <hip/hip_bf16.h>

#define N_NODES 50000
#define DIM 128
#define N_EDGES 600000
#define MAX_DEG 64   // degree ~ Poisson(12); P(>64) ~ 1e-30 for this fixed graph

typedef __attribute__((ext_vector_type(8))) short short8;
typedef __attribute__((ext_vector_type(4))) float f32x4;

__device__ __forceinline__ unsigned short f2bf_u(float f) {
    return __bfloat16_as_ushort(__float2bfloat16(f));
}

// ---------------------------------------------------------------------------
// Kernel 1: edge binning (blocks [0, 2344)) + weight transpose to bf16
// (blocks [2344, 2344+192)). Independent outputs, one launch.
// ---------------------------------------------------------------------------
#define FILL_BLOCKS ((N_EDGES + 255) / 256)   // 2344
#define PREP_BLOCKS 192                       // 49152 weight elements / 256

__global__ __launch_bounds__(256) void fill_prep(
    const int* __restrict__ ridx, int* __restrict__ cnt, int* __restrict__ elist,
    const float* __restrict__ W1, const float* __restrict__ W2,
    __hip_bfloat16* __restrict__ W1t, __hip_bfloat16* __restrict__ W2t) {
    int b = blockIdx.x;
    if (b < FILL_BLOCKS) {
        int e = b * 256 + threadIdx.x;
        if (e < N_EDGES) {
            int node = ridx[e];
            int pos = atomicAdd(&cnt[node], 1);
            if (pos < MAX_DEG) elist[(size_t)node * MAX_DEG + pos] = e;
        }
    } else {
        int t = (b - FILL_BLOCKS) * 256 + threadIdx.x;
        if (t < 256 * 128) {                    // W1 [256,128] -> W1t [128,256]
            int k = t >> 7, n = t & 127;
            W1t[n * 256 + k] = __float2bfloat16(W1[t]);
        } else {                                // W2 [128,128] -> W2t [128,128]
            int q = t - 256 * 128;
            int k = q >> 7, n = q & 127;
            W2t[n * 128 + k] = __float2bfloat16(W2[q]);
        }
    }
}

// ---------------------------------------------------------------------------
// Kernel 2: fused gather-aggregate + MLP. Block = 256 thr = 4 waves,
// M-tile = 128 rows, wave w owns rows [32w, 32w+32) — LDS region is
// wave-private, so NO __syncthreads anywhere.
//   Phase 1: per wave, 32 nodes; lane sums 2 dims (float2) over the node's
//            edge list (8-wide chunks -> 8 loads in flight), writes bf16
//            pair into sBuf row (agg half of the concat).
//   Phase 2: GEMM1 K=256: K in [0,128) from fp32 x (global, in-reg bf16
//            convert — identical rounding to the old prep pass), K in
//            [128,256) from sBuf. bias+relu -> overwrite own sBuf rows.
//   Phase 3: GEMM2 K=128 from sBuf, bias, fp32 store.
// mfma_f32_16x16x32_bf16. A-frag: A[m=lane&15][k=quad*8+j].
// B-frag: B[k=quad*8+j][n=lane&15]. C/D: col=lane&15, row=quad*4+reg.
// (fragment layouts carried over from the verified kernel, absmax 0.0625)
// sBuf stride 136 (272 B): ds_read_b128 rows r..r+15 at fixed col spread
// over banks 4r%32 — balanced, vs 16-way same-bank at stride 128.
// ---------------------------------------------------------------------------
__global__ __launch_bounds__(256) void fused_kernel(
    const float* __restrict__ x,
    const float* __restrict__ edge_attr,
    const int* __restrict__ elist,
    const int* __restrict__ cnt,
    const __hip_bfloat16* __restrict__ W1t,
    const float* __restrict__ b1,
    const __hip_bfloat16* __restrict__ W2t,
    const float* __restrict__ b2,
    float* __restrict__ out) {
    __shared__ __hip_bfloat16 sBuf[128][136];

    const int wave = threadIdx.x >> 6;
    const int lane = threadIdx.x & 63;
    const int quad = lane >> 4;
    const int l16  = lane & 15;
    const int rowBase = blockIdx.x * 128 + wave * 32;

    // ---- Phase 1: gather-aggregate into sBuf (wave-private rows) ----
    for (int i = 0; i < 32; i++) {
        const int node = rowBase + i;
        unsigned packed = 0u;
        if (node < N_NODES) {
            int deg = cnt[node];
            deg = deg < MAX_DEG ? deg : MAX_DEG;
            const int* el = elist + (size_t)node * MAX_DEG;
            float sx = 0.f, sy = 0.f;
            int j = 0;
            for (; j + 8 <= deg; j += 8) {
                int4 ea = *reinterpret_cast<const int4*>(el + j);
                int4 eb = *reinterpret_cast<const int4*>(el + j + 4);
                float2 v0 = *reinterpret_cast<const float2*>(edge_attr + (size_t)ea.x * DIM + lane * 2);
                float2 v1 = *reinterpret_cast<const float2*>(edge_attr + (size_t)ea.y * DIM + lane * 2);
                float2 v2 = *reinterpret_cast<const float2*>(edge_attr + (size_t)ea.z * DIM + lane * 2);
                float2 v3 = *reinterpret_cast<const float2*>(edge_attr + (size_t)ea.w * DIM + lane * 2);
                float2 v4 = *reinterpret_cast<const float2*>(edge_attr + (size_t)eb.x * DIM + lane * 2);
                float2 v5 = *reinterpret_cast<const float2*>(edge_attr + (size_t)eb.y * DIM + lane * 2);
                float2 v6 = *reinterpret_cast<const float2*>(edge_attr + (size_t)eb.z * DIM + lane * 2);
                float2 v7 = *reinterpret_cast<const float2*>(edge_attr + (size_t)eb.w * DIM + lane * 2);
                sx += ((v0.x + v1.x) + (v2.x + v3.x)) + ((v4.x + v5.x) + (v6.x + v7.x));
                sy += ((v0.y + v1.y) + (v2.y + v3.y)) + ((v4.y + v5.y) + (v6.y + v7.y));
            }
            if (j + 4 <= deg) {
                int4 ea = *reinterpret_cast<const int4*>(el + j);
                float2 v0 = *reinterpret_cast<const float2*>(edge_attr + (size_t)ea.x * DIM + lane * 2);
                float2 v1 = *reinterpret_cast<const float2*>(edge_attr + (size_t)ea.y * DIM + lane * 2);
                float2 v2 = *reinterpret_cast<const float2*>(edge_attr + (size_t)ea.z * DIM + lane * 2);
                float2 v3 = *reinterpret_cast<const float2*>(edge_attr + (size_t)ea.w * DIM + lane * 2);
                sx += (v0.x + v1.x) + (v2.x + v3.x);
                sy += (v0.y + v1.y) + (v2.y + v3.y);
                j += 4;
            }
            for (; j < deg; j++) {
                int e0 = el[j];
                float2 v0 = *reinterpret_cast<const float2*>(edge_attr + (size_t)e0 * DIM + lane * 2);
                sx += v0.x;
                sy += v0.y;
            }
            packed = ((unsigned)f2bf_u(sy) << 16) | (unsigned)f2bf_u(sx);
        }
        *reinterpret_cast<unsigned*>(&sBuf[wave * 32 + i][lane * 2]) = packed;
    }

    // ---- Phase 2: GEMM1  H = relu([x | agg] @ W1 + b1), K = 256 ----
    f32x4 accH[2][8] = {};
#pragma unroll
    for (int ks = 0; ks < 8; ks++) {
        const int k0 = ks * 32 + quad * 8;
        short8 a[2];
        if (ks < 4) {
            // x half: read fp32 directly, convert in-register
#pragma unroll
            for (int rt = 0; rt < 2; rt++) {
                int row = rowBase + rt * 16 + l16;
                row = row < N_NODES ? row : N_NODES - 1;
                const float* xp = x + (size_t)row * DIM + k0;
                f32x4 u = *reinterpret_cast<const f32x4*>(xp);
                f32x4 v = *reinterpret_cast<const f32x4*>(xp + 4);
                short8 av = { (short)f2bf_u(u[0]), (short)f2bf_u(u[1]),
                              (short)f2bf_u(u[2]), (short)f2bf_u(u[3]),
                              (short)f2bf_u(v[0]), (short)f2bf_u(v[1]),
                              (short)f2bf_u(v[2]), (short)f2bf_u(v[3]) };
                a[rt] = av;
            }
        } else {
            // agg half: from wave-private LDS rows
#pragma unroll
            for (int rt = 0; rt < 2; rt++) {
                int r = wave * 32 + rt * 16 + l16;
                a[rt] = *reinterpret_cast<const short8*>(&sBuf[r][k0 - 128]);
            }
        }
#pragma unroll
        for (int nt = 0; nt < 8; nt++) {
            short8 b = *reinterpret_cast<const short8*>(W1t + (nt * 16 + l16) * 256 + k0);
            accH[0][nt] = __builtin_amdgcn_mfma_f32_16x16x32_bf16(a[0], b, accH[0][nt], 0, 0, 0);
            accH[1][nt] = __builtin_amdgcn_mfma_f32_16x16x32_bf16(a[1], b, accH[1][nt], 0, 0, 0);
        }
    }

    // ---- bias + relu -> overwrite own sBuf rows (bf16) ----
#pragma unroll
    for (int nt = 0; nt < 8; nt++) {
        const float bias = b1[nt * 16 + l16];
#pragma unroll
        for (int rt = 0; rt < 2; rt++) {
#pragma unroll
            for (int i = 0; i < 4; i++) {
                float v = accH[rt][nt][i] + bias;
                v = v > 0.0f ? v : 0.0f;
                int r = wave * 32 + rt * 16 + quad * 4 + i;
                sBuf[r][nt * 16 + l16] = __float2bfloat16(v);
            }
        }
    }

    // ---- Phase 3: GEMM2  OUT = H @ W2 + b2, K = 128 ----
    f32x4 accO[2][8] = {};
#pragma unroll
    for (int ks = 0; ks < 4; ks++) {
        const int k0 = ks * 32 + quad * 8;
        short8 a[2];
#pragma unroll
        for (int rt = 0; rt < 2; rt++) {
            int r = wave * 32 + rt * 16 + l16;
            a[rt] = *reinterpret_cast<const short8*>(&sBuf[r][k0]);
        }
#pragma unroll
        for (int nt = 0; nt < 8; nt++) {
            short8 b = *reinterpret_cast<const short8*>(W2t + (nt * 16 + l16) * 128 + k0);
            accO[0][nt] = __builtin_amdgcn_mfma_f32_16x16x32_bf16(a[0], b, accO[0][nt], 0, 0, 0);
            accO[1][nt] = __builtin_amdgcn_mfma_f32_16x16x32_bf16(a[1], b, accO[1][nt], 0, 0, 0);
        }
    }

    // ---- bias + store (fp32) ----
#pragma unroll
    for (int nt = 0; nt < 8; nt++) {
        const float bias = b2[nt * 16 + l16];
#pragma unroll
        for (int rt = 0; rt < 2; rt++) {
#pragma unroll
            for (int i = 0; i < 4; i++) {
                int row = rowBase + rt * 16 + quad * 4 + i;
                if (row < N_NODES) {
                    out[(size_t)row * DIM + nt * 16 + l16] = accO[rt][nt][i] + bias;
                }
            }
        }
    }
}

extern "C" void kernel_launch(void* const* d_in, const int* in_sizes, int n_in,
                              void* d_out, int out_size, void* d_ws, size_t ws_size,
                              hipStream_t stream) {
    const float* x         = (const float*)d_in[0];
    const float* edge_attr = (const float*)d_in[1];
    const int*   ridx      = (const int*)d_in[2];
    const float* W1        = (const float*)d_in[3];
    const float* b1        = (const float*)d_in[4];
    const float* W2        = (const float*)d_in[5];
    const float* b2        = (const float*)d_in[6];
    float* out = (float*)d_out;

    // workspace layout (16B aligned):
    //   elist int[50000*64] | cnt int[50000] | W1t bf16[256*128] | W2t bf16[128*128]
    char* w = (char*)d_ws;
    int* elist = (int*)w;                     w += (size_t)N_NODES * MAX_DEG * 4;
    int* cnt   = (int*)w;                     w += (size_t)N_NODES * 4;
    __hip_bfloat16* W1t = (__hip_bfloat16*)w; w += 256 * 128 * 2;
    __hip_bfloat16* W2t = (__hip_bfloat16*)w;

    hipMemsetAsync(cnt, 0, (size_t)N_NODES * 4, stream);
    fill_prep<<<dim3(FILL_BLOCKS + PREP_BLOCKS), dim3(256), 0, stream>>>(
        ridx, cnt, elist, W1, W2, W1t, W2t);
    fused_kernel<<<dim3((N_NODES + 127) / 128), dim3(256), 0, stream>>>(
        x, edge_attr, elist, cnt, W1t, b1, W2t, b2, out);
}

// Round 2
// 531.517 us; speedup vs baseline: 1.0592x; 1.0592x over previous
//
#include <hip/hip_runtime.h>
#include <hip/hip_bf16.h>

#define N_NODES 50000
#define DIM 128
#define N_EDGES 600000
#define MAX_DEG 64   // degree ~ Poisson(12); P(>64) ~ 1e-30 for this fixed graph

typedef __attribute__((ext_vector_type(8))) short short8;
typedef __attribute__((ext_vector_type(4))) float f32x4;

__device__ __forceinline__ unsigned short f2bf_u(float f) {
    return __bfloat16_as_ushort(__float2bfloat16(f));
}

// ---------------------------------------------------------------------------
// Kernel 1: edge binning (blocks [0, 2344)) + weight transpose to bf16
// (blocks [2344, 2344+192)). Independent outputs, one launch.
// ---------------------------------------------------------------------------
#define FILL_BLOCKS ((N_EDGES + 255) / 256)   // 2344
#define PREP_BLOCKS 192                       // 49152 weight elements / 256

__global__ __launch_bounds__(256) void fill_prep(
    const int* __restrict__ ridx, int* __restrict__ cnt, int* __restrict__ elist,
    const float* __restrict__ W1, const float* __restrict__ W2,
    __hip_bfloat16* __restrict__ W1t, __hip_bfloat16* __restrict__ W2t) {
    int b = blockIdx.x;
    if (b < FILL_BLOCKS) {
        int e = b * 256 + threadIdx.x;
        if (e < N_EDGES) {
            int node = ridx[e];
            int pos = atomicAdd(&cnt[node], 1);
            if (pos < MAX_DEG) elist[(size_t)node * MAX_DEG + pos] = e;
        }
    } else {
        int t = (b - FILL_BLOCKS) * 256 + threadIdx.x;
        if (t < 256 * 128) {                    // W1 [256,128] -> W1t [128,256]
            int k = t >> 7, n = t & 127;
            W1t[n * 256 + k] = __float2bfloat16(W1[t]);
        } else {                                // W2 [128,128] -> W2t [128,128]
            int q = t - 256 * 128;
            int k = q >> 7, n = q & 127;
            W2t[n * 128 + k] = __float2bfloat16(W2[q]);
        }
    }
}

// ---------------------------------------------------------------------------
// Kernel 2: gather-aggregate. One wave per node (50000 waves, 12500 blocks —
// full latency hiding, ~195 waves/CU of work). Lane handles 2 dims (float2,
// 512 B contiguous per edge across the wave); each edge row read exactly
// once chip-wide. 8-wide ILP chunks. Sums fp32, writes packed bf16 pair to
// compact agg[node][128] (12.8 MB -> L2/L3-resident for the MLP kernel).
// ---------------------------------------------------------------------------
__global__ __launch_bounds__(256) void aggregate_kernel(
    const float* __restrict__ edge_attr,
    const int* __restrict__ elist,
    const int* __restrict__ cnt,
    __hip_bfloat16* __restrict__ agg) {
    const int node = blockIdx.x * 4 + (threadIdx.x >> 6);
    const int lane = threadIdx.x & 63;
    if (node >= N_NODES) return;
    int deg = cnt[node];
    deg = deg < MAX_DEG ? deg : MAX_DEG;
    const int* el = elist + (size_t)node * MAX_DEG;
    float sx = 0.f, sy = 0.f;
    int j = 0;
    for (; j + 8 <= deg; j += 8) {
        int4 ea = *reinterpret_cast<const int4*>(el + j);
        int4 eb = *reinterpret_cast<const int4*>(el + j + 4);
        float2 v0 = *reinterpret_cast<const float2*>(edge_attr + (size_t)ea.x * DIM + lane * 2);
        float2 v1 = *reinterpret_cast<const float2*>(edge_attr + (size_t)ea.y * DIM + lane * 2);
        float2 v2 = *reinterpret_cast<const float2*>(edge_attr + (size_t)ea.z * DIM + lane * 2);
        float2 v3 = *reinterpret_cast<const float2*>(edge_attr + (size_t)ea.w * DIM + lane * 2);
        float2 v4 = *reinterpret_cast<const float2*>(edge_attr + (size_t)eb.x * DIM + lane * 2);
        float2 v5 = *reinterpret_cast<const float2*>(edge_attr + (size_t)eb.y * DIM + lane * 2);
        float2 v6 = *reinterpret_cast<const float2*>(edge_attr + (size_t)eb.z * DIM + lane * 2);
        float2 v7 = *reinterpret_cast<const float2*>(edge_attr + (size_t)eb.w * DIM + lane * 2);
        sx += ((v0.x + v1.x) + (v2.x + v3.x)) + ((v4.x + v5.x) + (v6.x + v7.x));
        sy += ((v0.y + v1.y) + (v2.y + v3.y)) + ((v4.y + v5.y) + (v6.y + v7.y));
    }
    if (j + 4 <= deg) {
        int4 ea = *reinterpret_cast<const int4*>(el + j);
        float2 v0 = *reinterpret_cast<const float2*>(edge_attr + (size_t)ea.x * DIM + lane * 2);
        float2 v1 = *reinterpret_cast<const float2*>(edge_attr + (size_t)ea.y * DIM + lane * 2);
        float2 v2 = *reinterpret_cast<const float2*>(edge_attr + (size_t)ea.z * DIM + lane * 2);
        float2 v3 = *reinterpret_cast<const float2*>(edge_attr + (size_t)ea.w * DIM + lane * 2);
        sx += (v0.x + v1.x) + (v2.x + v3.x);
        sy += (v0.y + v1.y) + (v2.y + v3.y);
        j += 4;
    }
    for (; j < deg; j++) {
        int e0 = el[j];
        float2 v0 = *reinterpret_cast<const float2*>(edge_attr + (size_t)e0 * DIM + lane * 2);
        sx += v0.x;
        sy += v0.y;
    }
    unsigned packed = ((unsigned)f2bf_u(sy) << 16) | (unsigned)f2bf_u(sx);
    *reinterpret_cast<unsigned*>(agg + (size_t)node * DIM + lane * 2) = packed;
}

// ---------------------------------------------------------------------------
// Kernel 3: MLP. Block = 256 thr = 4 waves, M-tile = 64 rows; wave w owns
// rows [16w, 16w+16) — LDS region is wave-private, NO __syncthreads.
//   GEMM1 K=256: K in [0,128) from fp32 x (in-reg bf16 convert, identical
//   RNE rounding to the old prep pass); K in [128,256) from bf16 agg
//   (L2/L3-resident). bias+relu -> sH (bf16). GEMM2 K=128 from sH, bias,
//   fp32 store. Grid = 782 blocks -> 3125 waves (2x round-0 parallelism).
// mfma_f32_16x16x32_bf16. A-frag: A[m=lane&15][k=quad*8+j].
// B-frag: B[k=quad*8+j][n=lane&15]. C/D: col=lane&15, row=quad*4+reg.
// (fragment layouts carried over from the verified kernel, absmax 0.0625)
// ---------------------------------------------------------------------------
__global__ __launch_bounds__(256) void mlp_kernel(
    const float* __restrict__ x,
    const __hip_bfloat16* __restrict__ agg,
    const __hip_bfloat16* __restrict__ W1t,
    const float* __restrict__ b1,
    const __hip_bfloat16* __restrict__ W2t,
    const float* __restrict__ b2,
    float* __restrict__ out) {
    __shared__ __hip_bfloat16 sH[64][136];  // +8 pad; 17.4 KB

    const int wave = threadIdx.x >> 6;
    const int lane = threadIdx.x & 63;
    const int quad = lane >> 4;
    const int l16  = lane & 15;
    const int rowBase = blockIdx.x * 64 + wave * 16;

    int rowA = rowBase + l16;                 // A-fragment row for this lane
    rowA = rowA < N_NODES ? rowA : N_NODES - 1;

    // ---- GEMM1: H = relu([x | agg] @ W1 + b1), K = 256 ----
    f32x4 accH[8] = {};
#pragma unroll
    for (int ks = 0; ks < 8; ks++) {
        const int k0 = ks * 32 + quad * 8;
        short8 a;
        if (ks < 4) {
            const float* xp = x + (size_t)rowA * DIM + k0;
            f32x4 u = *reinterpret_cast<const f32x4*>(xp);
            f32x4 v = *reinterpret_cast<const f32x4*>(xp + 4);
            short8 av = { (short)f2bf_u(u[0]), (short)f2bf_u(u[1]),
                          (short)f2bf_u(u[2]), (short)f2bf_u(u[3]),
                          (short)f2bf_u(v[0]), (short)f2bf_u(v[1]),
                          (short)f2bf_u(v[2]), (short)f2bf_u(v[3]) };
            a = av;
        } else {
            a = *reinterpret_cast<const short8*>(agg + (size_t)rowA * DIM + (k0 - 128));
        }
#pragma unroll
        for (int nt = 0; nt < 8; nt++) {
            short8 b = *reinterpret_cast<const short8*>(W1t + (nt * 16 + l16) * 256 + k0);
            accH[nt] = __builtin_amdgcn_mfma_f32_16x16x32_bf16(a, b, accH[nt], 0, 0, 0);
        }
    }

    // ---- bias + relu -> wave-private sH rows (bf16) ----
#pragma unroll
    for (int nt = 0; nt < 8; nt++) {
        const float bias = b1[nt * 16 + l16];
#pragma unroll
        for (int i = 0; i < 4; i++) {
            float v = accH[nt][i] + bias;
            v = v > 0.0f ? v : 0.0f;
            int r = wave * 16 + quad * 4 + i;
            sH[r][nt * 16 + l16] = __float2bfloat16(v);
        }
    }
    // wave-private rows: within-wave ds_write -> ds_read ordering is handled
    // by the compiler's lgkmcnt; no barrier needed.

    // ---- GEMM2: OUT = H @ W2 + b2, K = 128 ----
    f32x4 accO[8] = {};
#pragma unroll
    for (int ks = 0; ks < 4; ks++) {
        const int k0 = ks * 32 + quad * 8;
        short8 a = *reinterpret_cast<const short8*>(&sH[wave * 16 + l16][k0]);
#pragma unroll
        for (int nt = 0; nt < 8; nt++) {
            short8 b = *reinterpret_cast<const short8*>(W2t + (nt * 16 + l16) * 128 + k0);
            accO[nt] = __builtin_amdgcn_mfma_f32_16x16x32_bf16(a, b, accO[nt], 0, 0, 0);
        }
    }

    // ---- bias + store (fp32) ----
#pragma unroll
    for (int nt = 0; nt < 8; nt++) {
        const float bias = b2[nt * 16 + l16];
#pragma unroll
        for (int i = 0; i < 4; i++) {
            int row = rowBase + quad * 4 + i;
            if (row < N_NODES) {
                out[(size_t)row * DIM + nt * 16 + l16] = accO[nt][i] + bias;
            }
        }
    }
}

extern "C" void kernel_launch(void* const* d_in, const int* in_sizes, int n_in,
                              void* d_out, int out_size, void* d_ws, size_t ws_size,
                              hipStream_t stream) {
    const float* x         = (const float*)d_in[0];
    const float* edge_attr = (const float*)d_in[1];
    const int*   ridx      = (const int*)d_in[2];
    const float* W1        = (const float*)d_in[3];
    const float* b1        = (const float*)d_in[4];
    const float* W2        = (const float*)d_in[5];
    const float* b2        = (const float*)d_in[6];
    float* out = (float*)d_out;

    // workspace layout (16B aligned):
    //   elist int[50000*64] | cnt int[50000] | agg bf16[50000*128]
    //   W1t bf16[256*128] | W2t bf16[128*128]
    char* w = (char*)d_ws;
    int* elist = (int*)w;                     w += (size_t)N_NODES * MAX_DEG * 4;
    int* cnt   = (int*)w;                     w += (size_t)N_NODES * 4;
    __hip_bfloat16* agg = (__hip_bfloat16*)w; w += (size_t)N_NODES * DIM * 2;
    __hip_bfloat16* W1t = (__hip_bfloat16*)w; w += 256 * 128 * 2;
    __hip_bfloat16* W2t = (__hip_bfloat16*)w;

    hipMemsetAsync(cnt, 0, (size_t)N_NODES * 4, stream);
    fill_prep<<<dim3(FILL_BLOCKS + PREP_BLOCKS), dim3(256), 0, stream>>>(
        ridx, cnt, elist, W1, W2, W1t, W2t);
    aggregate_kernel<<<dim3((N_NODES + 3) / 4), dim3(256), 0, stream>>>(
        edge_attr, elist, cnt, agg);
    mlp_kernel<<<dim3((N_NODES + 63) / 64), dim3(256), 0, stream>>>(
        x, agg, W1t, b1, W2t, b2, out);
}

// Round 3
// 519.333 us; speedup vs baseline: 1.0841x; 1.0235x over previous
//
#include <hip/hip_runtime.h>
#include <hip/hip_bf16.h>

#define N_NODES 50000
#define DIM 128
#define N_EDGES 600000
#define MAX_DEG 64   // degree ~ Poisson(12); P(>64) ~ 1e-30 for this fixed graph

typedef __attribute__((ext_vector_type(8))) short short8;
typedef __attribute__((ext_vector_type(4))) float f32x4;

__device__ __forceinline__ unsigned short f2bf_u(float f) {
    return __bfloat16_as_ushort(__float2bfloat16(f));
}

// ---------------------------------------------------------------------------
// Kernel 1: edge binning (blocks [0, 2344)) + weight transpose to bf16
// (blocks [2344, 2344+192)). Independent outputs, one launch.
// ---------------------------------------------------------------------------
#define FILL_BLOCKS ((N_EDGES + 255) / 256)   // 2344
#define PREP_BLOCKS 192                       // 49152 weight elements / 256

__global__ __launch_bounds__(256) void fill_prep(
    const int* __restrict__ ridx, int* __restrict__ cnt, int* __restrict__ elist,
    const float* __restrict__ W1, const float* __restrict__ W2,
    __hip_bfloat16* __restrict__ W1t, __hip_bfloat16* __restrict__ W2t) {
    int b = blockIdx.x;
    if (b < FILL_BLOCKS) {
        int e = b * 256 + threadIdx.x;
        if (e < N_EDGES) {
            int node = ridx[e];
            int pos = atomicAdd(&cnt[node], 1);
            if (pos < MAX_DEG) elist[(size_t)node * MAX_DEG + pos] = e;
        }
    } else {
        int t = (b - FILL_BLOCKS) * 256 + threadIdx.x;
        if (t < 256 * 128) {                    // W1 [256,128] -> W1t [128,256]
            int k = t >> 7, n = t & 127;
            W1t[n * 256 + k] = __float2bfloat16(W1[t]);
        } else {                                // W2 [128,128] -> W2t [128,128]
            int q = t - 256 * 128;
            int k = q >> 7, n = q & 127;
            W2t[n * 128 + k] = __float2bfloat16(W2[q]);
        }
    }
}

// ---------------------------------------------------------------------------
// Kernel 2: fused gather + MLP. Block = 512 thr = 8 waves, M-tile = 32 nodes.
//
// Phase A (gather + x-stage): wave w owns local rows [4w, 4w+4). For each of
//   its 4 nodes the wave sums edge_attr rows (lane = 2 dims, float2; 8-wide
//   ILP chunks; 512 B contiguous per edge across the wave) AND stages the x
//   row (fp32 -> bf16 in-register, RNE — same rounding as the old prep pass)
//   into the concat LDS tile sIn[32][x:0..128 | agg:128..256].
//   12504 gather waves chip-wide — same parallelism as the round-2 split
//   aggregate kernel (round-1's 32-nodes-per-wave fusion was latency-bound).
//
// Phase B (GEMM1, K=256): waves as 2(M)x4(N); wave (wm,wn) computes rows
//   [16wm,16wm+16) x cols [32wn,32wn+32) from sIn + W1t. bias+relu -> sH.
// Phase C (GEMM2, K=128): same tiling from sH + W2t, bias, fp32 store.
//
// mfma_f32_16x16x32_bf16. A-frag: A[m=lane&15][k=quad*8+j].
// B-frag: B[k=quad*8+j][n=lane&15]. C/D: col=lane&15, row=quad*4+reg.
// (fragment layouts carried over from the verified kernel, absmax 0.0625)
// sIn stride 264 (528 B = 132 dw, %32 = 4) and sH stride 136 (272 B = 68 dw,
// %32 = 4): 16 rows at fixed col spread over 8 banks x2 = 2-way, free.
// ---------------------------------------------------------------------------
__global__ __launch_bounds__(512) void gather_mlp(
    const float* __restrict__ x,
    const float* __restrict__ edge_attr,
    const int* __restrict__ elist,
    const int* __restrict__ cnt,
    const __hip_bfloat16* __restrict__ W1t,
    const float* __restrict__ b1,
    const __hip_bfloat16* __restrict__ W2t,
    const float* __restrict__ b2,
    float* __restrict__ out) {
    __shared__ __hip_bfloat16 sIn[32][264];  // [x | agg], +8 pad; 16.9 KB
    __shared__ __hip_bfloat16 sH[32][136];   // H tile, +8 pad; 8.7 KB

    const int wave = threadIdx.x >> 6;   // 0..7
    const int lane = threadIdx.x & 63;
    const int quad = lane >> 4;
    const int l16  = lane & 15;
    const int rowBase = blockIdx.x * 32;

    // ---- Phase A: gather-aggregate + x staging (wave-private rows) ----
    for (int i = 0; i < 4; i++) {
        const int r = wave * 4 + i;
        const int node = rowBase + r;
        unsigned px = 0u, pa = 0u;
        if (node < N_NODES) {
            // x row: fp32 -> bf16 pair
            float2 xv = *reinterpret_cast<const float2*>(x + (size_t)node * DIM + lane * 2);
            px = ((unsigned)f2bf_u(xv.y) << 16) | (unsigned)f2bf_u(xv.x);
            // edge gather
            int deg = cnt[node];
            deg = deg < MAX_DEG ? deg : MAX_DEG;
            const int* el = elist + (size_t)node * MAX_DEG;
            float sx = 0.f, sy = 0.f;
            int j = 0;
            for (; j + 8 <= deg; j += 8) {
                int4 ea = *reinterpret_cast<const int4*>(el + j);
                int4 eb = *reinterpret_cast<const int4*>(el + j + 4);
                float2 v0 = *reinterpret_cast<const float2*>(edge_attr + (size_t)ea.x * DIM + lane * 2);
                float2 v1 = *reinterpret_cast<const float2*>(edge_attr + (size_t)ea.y * DIM + lane * 2);
                float2 v2 = *reinterpret_cast<const float2*>(edge_attr + (size_t)ea.z * DIM + lane * 2);
                float2 v3 = *reinterpret_cast<const float2*>(edge_attr + (size_t)ea.w * DIM + lane * 2);
                float2 v4 = *reinterpret_cast<const float2*>(edge_attr + (size_t)eb.x * DIM + lane * 2);
                float2 v5 = *reinterpret_cast<const float2*>(edge_attr + (size_t)eb.y * DIM + lane * 2);
                float2 v6 = *reinterpret_cast<const float2*>(edge_attr + (size_t)eb.z * DIM + lane * 2);
                float2 v7 = *reinterpret_cast<const float2*>(edge_attr + (size_t)eb.w * DIM + lane * 2);
                sx += ((v0.x + v1.x) + (v2.x + v3.x)) + ((v4.x + v5.x) + (v6.x + v7.x));
                sy += ((v0.y + v1.y) + (v2.y + v3.y)) + ((v4.y + v5.y) + (v6.y + v7.y));
            }
            if (j + 4 <= deg) {
                int4 ea = *reinterpret_cast<const int4*>(el + j);
                float2 v0 = *reinterpret_cast<const float2*>(edge_attr + (size_t)ea.x * DIM + lane * 2);
                float2 v1 = *reinterpret_cast<const float2*>(edge_attr + (size_t)ea.y * DIM + lane * 2);
                float2 v2 = *reinterpret_cast<const float2*>(edge_attr + (size_t)ea.z * DIM + lane * 2);
                float2 v3 = *reinterpret_cast<const float2*>(edge_attr + (size_t)ea.w * DIM + lane * 2);
                sx += (v0.x + v1.x) + (v2.x + v3.x);
                sy += (v0.y + v1.y) + (v2.y + v3.y);
                j += 4;
            }
            for (; j < deg; j++) {
                int e0 = el[j];
                float2 v0 = *reinterpret_cast<const float2*>(edge_attr + (size_t)e0 * DIM + lane * 2);
                sx += v0.x;
                sy += v0.y;
            }
            pa = ((unsigned)f2bf_u(sy) << 16) | (unsigned)f2bf_u(sx);
        }
        *reinterpret_cast<unsigned*>(&sIn[r][lane * 2]) = px;
        *reinterpret_cast<unsigned*>(&sIn[r][128 + lane * 2]) = pa;
    }
    __syncthreads();

    const int wm = wave >> 2;            // 0..1
    const int colBase = (wave & 3) * 32; // 0,32,64,96

    // ---- Phase B: GEMM1  H = relu([x | agg] @ W1 + b1), K = 256 ----
    f32x4 accH[2] = {};
#pragma unroll
    for (int ks = 0; ks < 8; ks++) {
        const int k0 = ks * 32 + quad * 8;
        short8 a = *reinterpret_cast<const short8*>(&sIn[wm * 16 + l16][k0]);
#pragma unroll
        for (int nt = 0; nt < 2; nt++) {
            short8 b = *reinterpret_cast<const short8*>(W1t + (colBase + nt * 16 + l16) * 256 + k0);
            accH[nt] = __builtin_amdgcn_mfma_f32_16x16x32_bf16(a, b, accH[nt], 0, 0, 0);
        }
    }

    // bias + relu -> sH (bf16)
#pragma unroll
    for (int nt = 0; nt < 2; nt++) {
        const float bias = b1[colBase + nt * 16 + l16];
#pragma unroll
        for (int i = 0; i < 4; i++) {
            float v = accH[nt][i] + bias;
            v = v > 0.0f ? v : 0.0f;
            sH[wm * 16 + quad * 4 + i][colBase + nt * 16 + l16] = __float2bfloat16(v);
        }
    }
    __syncthreads();

    // ---- Phase C: GEMM2  OUT = H @ W2 + b2, K = 128 ----
    f32x4 accO[2] = {};
#pragma unroll
    for (int ks = 0; ks < 4; ks++) {
        const int k0 = ks * 32 + quad * 8;
        short8 a = *reinterpret_cast<const short8*>(&sH[wm * 16 + l16][k0]);
#pragma unroll
        for (int nt = 0; nt < 2; nt++) {
            short8 b = *reinterpret_cast<const short8*>(W2t + (colBase + nt * 16 + l16) * 128 + k0);
            accO[nt] = __builtin_amdgcn_mfma_f32_16x16x32_bf16(a, b, accO[nt], 0, 0, 0);
        }
    }

    // ---- bias + store (fp32) ----
#pragma unroll
    for (int nt = 0; nt < 2; nt++) {
        const float bias = b2[colBase + nt * 16 + l16];
#pragma unroll
        for (int i = 0; i < 4; i++) {
            int row = rowBase + wm * 16 + quad * 4 + i;
            if (row < N_NODES) {
                out[(size_t)row * DIM + colBase + nt * 16 + l16] = accO[nt][i] + bias;
            }
        }
    }
}

extern "C" void kernel_launch(void* const* d_in, const int* in_sizes, int n_in,
                              void* d_out, int out_size, void* d_ws, size_t ws_size,
                              hipStream_t stream) {
    const float* x         = (const float*)d_in[0];
    const float* edge_attr = (const float*)d_in[1];
    const int*   ridx      = (const int*)d_in[2];
    const float* W1        = (const float*)d_in[3];
    const float* b1        = (const float*)d_in[4];
    const float* W2        = (const float*)d_in[5];
    const float* b2        = (const float*)d_in[6];
    float* out = (float*)d_out;

    // workspace layout (16B aligned):
    //   elist int[50000*64] | cnt int[50000] | W1t bf16[256*128] | W2t bf16[128*128]
    char* w = (char*)d_ws;
    int* elist = (int*)w;                     w += (size_t)N_NODES * MAX_DEG * 4;
    int* cnt   = (int*)w;                     w += (size_t)N_NODES * 4;
    __hip_bfloat16* W1t = (__hip_bfloat16*)w; w += 256 * 128 * 2;
    __hip_bfloat16* W2t = (__hip_bfloat16*)w;

    hipMemsetAsync(cnt, 0, (size_t)N_NODES * 4, stream);
    fill_prep<<<dim3(FILL_BLOCKS + PREP_BLOCKS), dim3(256), 0, stream>>>(
        ridx, cnt, elist, W1, W2, W1t, W2t);
    gather_mlp<<<dim3((N_NODES + 31) / 32), dim3(512), 0, stream>>>(
        x, edge_attr, elist, cnt, W1t, b1, W2t, b2, out);
}

// Round 4
// 514.223 us; speedup vs baseline: 1.0948x; 1.0099x over previous
//
#include <hip/hip_runtime.h>
#include <hip/hip_bf16.h>

#define N_NODES 50000
#define DIM 128
#define N_EDGES 600000
#define MAX_DEG 64   // degree ~ Poisson(12); P(>64) ~ 1e-30 for this fixed graph

typedef __attribute__((ext_vector_type(8))) short short8;
typedef __attribute__((ext_vector_type(4))) float f32x4;

__device__ __forceinline__ unsigned short f2bf_u(float f) {
    return __bfloat16_as_ushort(__float2bfloat16(f));
}

__device__ __forceinline__ uint2 pack4(f32x4 v) {
    ushort2 a = { f2bf_u(v[0]), f2bf_u(v[1]) };
    ushort2 b = { f2bf_u(v[2]), f2bf_u(v[3]) };
    uint2 r = { *reinterpret_cast<unsigned*>(&a), *reinterpret_cast<unsigned*>(&b) };
    return r;
}

// Clamped-index edge accumulate: lanes past deg read edge 0 (always valid,
// L1-hot) and select-zero the contribution — no divergent branches.
__device__ __forceinline__ void acc_edge(f32x4& s, const float* __restrict__ ea,
                                         int e, int k, int deg, int d0) {
    const int es = k < deg ? e : 0;
    f32x4 v = *reinterpret_cast<const f32x4*>(ea + (size_t)es * DIM + d0);
    const bool p = k < deg;
    s[0] += p ? v[0] : 0.f;
    s[1] += p ? v[1] : 0.f;
    s[2] += p ? v[2] : 0.f;
    s[3] += p ? v[3] : 0.f;
}

// ---------------------------------------------------------------------------
// Kernel 1: edge binning (blocks [0, 2344)) + weight transpose to bf16
// (blocks [2344, 2344+192)). Independent outputs, one launch.
// ---------------------------------------------------------------------------
#define FILL_BLOCKS ((N_EDGES + 255) / 256)   // 2344
#define PREP_BLOCKS 192                       // 49152 weight elements / 256

__global__ __launch_bounds__(256) void fill_prep(
    const int* __restrict__ ridx, int* __restrict__ cnt, int* __restrict__ elist,
    const float* __restrict__ W1, const float* __restrict__ W2,
    __hip_bfloat16* __restrict__ W1t, __hip_bfloat16* __restrict__ W2t) {
    int b = blockIdx.x;
    if (b < FILL_BLOCKS) {
        int e = b * 256 + threadIdx.x;
        if (e < N_EDGES) {
            int node = ridx[e];
            int pos = atomicAdd(&cnt[node], 1);
            if (pos < MAX_DEG) elist[(size_t)node * MAX_DEG + pos] = e;
        }
    } else {
        int t = (b - FILL_BLOCKS) * 256 + threadIdx.x;
        if (t < 256 * 128) {                    // W1 [256,128] -> W1t [128,256]
            int k = t >> 7, n = t & 127;
            W1t[n * 256 + k] = __float2bfloat16(W1[t]);
        } else {                                // W2 [128,128] -> W2t [128,128]
            int q = t - 256 * 128;
            int k = q >> 7, n = q & 127;
            W2t[n * 128 + k] = __float2bfloat16(W2[q]);
        }
    }
}

// ---------------------------------------------------------------------------
// Kernel 2: fused gather + MLP. Block = 512 thr = 8 waves, M-tile = 32 nodes.
//
// Phase A (gather + x-stage), HALF-WAVE form: lane covers 4 dims (float4);
//   lanes 0-31 and 32-63 process two different nodes simultaneously, so one
//   instruction stream carries 2 independent memory chains and each edge-load
//   instruction fetches 1 KB (2 x 512 B rows). Wave covers its 4 rows in 2
//   interleaved it-streams. elist int4s for the first 16 edges are loaded
//   SPECULATIVELY upfront (always in-bounds of the MAX_DEG bin), removing the
//   dependent elist->edge round-trip; out-of-degree slots clamp to edge 0 and
//   select-zero (no branches). Dynamic tail loop only for deg>16 (~10%).
//   12504 gather half-wave pairs chip-wide (parallelism kept from round 2/3).
//
// Phase B (GEMM1, K=256): waves as 2(M)x4(N); wave (wm,wn) computes rows
//   [16wm,16wm+16) x cols [32wn,32wn+32) from sIn + W1t. bias+relu -> sH.
// Phase C (GEMM2, K=128): same tiling from sH + W2t, bias, fp32 store.
//
// mfma_f32_16x16x32_bf16. A-frag: A[m=lane&15][k=quad*8+j].
// B-frag: B[k=quad*8+j][n=lane&15]. C/D: col=lane&15, row=quad*4+reg.
// (fragment layouts carried over from the verified kernel, absmax 0.0625)
// sIn stride 264 (528 B) and sH stride 136 (272 B): 16-row reads at fixed
// col land 2-way per bank (free, m136).
// ---------------------------------------------------------------------------
__global__ __launch_bounds__(512) void gather_mlp(
    const float* __restrict__ x,
    const float* __restrict__ edge_attr,
    const int* __restrict__ elist,
    const int* __restrict__ cnt,
    const __hip_bfloat16* __restrict__ W1t,
    const float* __restrict__ b1,
    const __hip_bfloat16* __restrict__ W2t,
    const float* __restrict__ b2,
    float* __restrict__ out) {
    __shared__ __hip_bfloat16 sIn[32][264];  // [x | agg], +8 pad; 16.9 KB
    __shared__ __hip_bfloat16 sH[32][136];   // H tile, +8 pad; 8.7 KB

    const int wave = threadIdx.x >> 6;   // 0..7
    const int lane = threadIdx.x & 63;
    const int quad = lane >> 4;
    const int l16  = lane & 15;
    const int rowBase = blockIdx.x * 32;

    // ---- Phase A: half-wave gather-aggregate + x staging ----
    {
        const int h   = lane >> 5;       // half-wave id
        const int l32 = lane & 31;
        const int d0  = l32 * 4;         // this lane's 4 dims

        const int r0 = wave * 4 + h;     // stream 0 row
        const int r1 = r0 + 2;           // stream 1 row
        const int n0 = rowBase + r0;
        const int n1 = rowBase + r1;
        const int nc0 = n0 < N_NODES ? n0 : N_NODES - 1;
        const int nc1 = n1 < N_NODES ? n1 : N_NODES - 1;

        // x rows: independent 16 B loads, issued first
        f32x4 xv0 = *reinterpret_cast<const f32x4*>(x + (size_t)nc0 * DIM + d0);
        f32x4 xv1 = *reinterpret_cast<const f32x4*>(x + (size_t)nc1 * DIM + d0);

        int deg0 = cnt[nc0];
        int deg1 = cnt[nc1];
        deg0 = n0 < N_NODES ? (deg0 < MAX_DEG ? deg0 : MAX_DEG) : 0;
        deg1 = n1 < N_NODES ? (deg1 < MAX_DEG ? deg1 : MAX_DEG) : 0;

        const int* el0 = elist + (size_t)nc0 * MAX_DEG;
        const int* el1 = elist + (size_t)nc1 * MAX_DEG;

        // speculative first-16 edge indices for both streams (always in-bounds)
        int4 q0[4], q1[4];
#pragma unroll
        for (int c = 0; c < 4; c++) {
            q0[c] = *reinterpret_cast<const int4*>(el0 + c * 4);
            q1[c] = *reinterpret_cast<const int4*>(el1 + c * 4);
        }

        f32x4 s0 = {}, s1 = {};
#pragma unroll
        for (int c = 0; c < 4; c++) {
            acc_edge(s0, edge_attr, q0[c].x, c * 4 + 0, deg0, d0);
            acc_edge(s1, edge_attr, q1[c].x, c * 4 + 0, deg1, d0);
            acc_edge(s0, edge_attr, q0[c].y, c * 4 + 1, deg0, d0);
            acc_edge(s1, edge_attr, q1[c].y, c * 4 + 1, deg1, d0);
            acc_edge(s0, edge_attr, q0[c].z, c * 4 + 2, deg0, d0);
            acc_edge(s1, edge_attr, q1[c].z, c * 4 + 2, deg1, d0);
            acc_edge(s0, edge_attr, q0[c].w, c * 4 + 3, deg0, d0);
            acc_edge(s1, edge_attr, q1[c].w, c * 4 + 3, deg1, d0);
        }
        // rare tails (deg > 16)
        for (int j = 16; j < deg0; j++) {
            f32x4 v = *reinterpret_cast<const f32x4*>(edge_attr + (size_t)el0[j] * DIM + d0);
            s0[0] += v[0]; s0[1] += v[1]; s0[2] += v[2]; s0[3] += v[3];
        }
        for (int j = 16; j < deg1; j++) {
            f32x4 v = *reinterpret_cast<const f32x4*>(edge_attr + (size_t)el1[j] * DIM + d0);
            s1[0] += v[0]; s1[1] += v[1]; s1[2] += v[2]; s1[3] += v[3];
        }

        *reinterpret_cast<uint2*>(&sIn[r0][d0])       = pack4(xv0);
        *reinterpret_cast<uint2*>(&sIn[r0][128 + d0]) = pack4(s0);
        *reinterpret_cast<uint2*>(&sIn[r1][d0])       = pack4(xv1);
        *reinterpret_cast<uint2*>(&sIn[r1][128 + d0]) = pack4(s1);
    }
    __syncthreads();

    const int wm = wave >> 2;            // 0..1
    const int colBase = (wave & 3) * 32; // 0,32,64,96

    // ---- Phase B: GEMM1  H = relu([x | agg] @ W1 + b1), K = 256 ----
    f32x4 accH[2] = {};
#pragma unroll
    for (int ks = 0; ks < 8; ks++) {
        const int k0 = ks * 32 + quad * 8;
        short8 a = *reinterpret_cast<const short8*>(&sIn[wm * 16 + l16][k0]);
#pragma unroll
        for (int nt = 0; nt < 2; nt++) {
            short8 b = *reinterpret_cast<const short8*>(W1t + (colBase + nt * 16 + l16) * 256 + k0);
            accH[nt] = __builtin_amdgcn_mfma_f32_16x16x32_bf16(a, b, accH[nt], 0, 0, 0);
        }
    }

    // bias + relu -> sH (bf16)
#pragma unroll
    for (int nt = 0; nt < 2; nt++) {
        const float bias = b1[colBase + nt * 16 + l16];
#pragma unroll
        for (int i = 0; i < 4; i++) {
            float v = accH[nt][i] + bias;
            v = v > 0.0f ? v : 0.0f;
            sH[wm * 16 + quad * 4 + i][colBase + nt * 16 + l16] = __float2bfloat16(v);
        }
    }
    __syncthreads();

    // ---- Phase C: GEMM2  OUT = H @ W2 + b2, K = 128 ----
    f32x4 accO[2] = {};
#pragma unroll
    for (int ks = 0; ks < 4; ks++) {
        const int k0 = ks * 32 + quad * 8;
        short8 a = *reinterpret_cast<const short8*>(&sH[wm * 16 + l16][k0]);
#pragma unroll
        for (int nt = 0; nt < 2; nt++) {
            short8 b = *reinterpret_cast<const short8*>(W2t + (colBase + nt * 16 + l16) * 128 + k0);
            accO[nt] = __builtin_amdgcn_mfma_f32_16x16x32_bf16(a, b, accO[nt], 0, 0, 0);
        }
    }

    // ---- bias + store (fp32) ----
#pragma unroll
    for (int nt = 0; nt < 2; nt++) {
        const float bias = b2[colBase + nt * 16 + l16];
#pragma unroll
        for (int i = 0; i < 4; i++) {
            int row = rowBase + wm * 16 + quad * 4 + i;
            if (row < N_NODES) {
                out[(size_t)row * DIM + colBase + nt * 16 + l16] = accO[nt][i] + bias;
            }
        }
    }
}

extern "C" void kernel_launch(void* const* d_in, const int* in_sizes, int n_in,
                              void* d_out, int out_size, void* d_ws, size_t ws_size,
                              hipStream_t stream) {
    const float* x         = (const float*)d_in[0];
    const float* edge_attr = (const float*)d_in[1];
    const int*   ridx      = (const int*)d_in[2];
    const float* W1        = (const float*)d_in[3];
    const float* b1        = (const float*)d_in[4];
    const float* W2        = (const float*)d_in[5];
    const float* b2        = (const float*)d_in[6];
    float* out = (float*)d_out;

    // workspace layout (16B aligned):
    //   elist int[50000*64] | cnt int[50000] | W1t bf16[256*128] | W2t bf16[128*128]
    char* w = (char*)d_ws;
    int* elist = (int*)w;                     w += (size_t)N_NODES * MAX_DEG * 4;
    int* cnt   = (int*)w;                     w += (size_t)N_NODES * 4;
    __hip_bfloat16* W1t = (__hip_bfloat16*)w; w += 256 * 128 * 2;
    __hip_bfloat16* W2t = (__hip_bfloat16*)w;

    hipMemsetAsync(cnt, 0, (size_t)N_NODES * 4, stream);
    fill_prep<<<dim3(FILL_BLOCKS + PREP_BLOCKS), dim3(256), 0, stream>>>(
        ridx, cnt, elist, W1, W2, W1t, W2t);
    gather_mlp<<<dim3((N_NODES + 31) / 32), dim3(512), 0, stream>>>(
        x, edge_attr, elist, cnt, W1t, b1, W2t, b2, out);
}